// Round 2
// baseline (25921.127 us; speedup 1.0000x reference)
//
#include <hip/hip_runtime.h>
#include <hip/hip_bf16.h>

// Problem dims
constexpr int kH  = 2048;          // hidden
constexpr int kD  = 1024;          // input dim
constexpr int kT  = 4096;          // timesteps
constexpr int kTH = 3 * kH;        // 6144 gate rows
constexpr int kNB = 256;           // GRU grid blocks (one per CU, BOTH sequences)

// ---------------------------------------------------------------------------
// Round-8 post-mortem (19.2 ms, +0.43 us/step vs r7): tagged publish is right
// but same-step direct polling guarantees several failed 16 KB sweeps per
// block per step (data cannot be visible on the first poll). Also VGPR stayed
// 128: 8-wave blocks always run >=2 waves/SIMD so launch_bounds(512,1) could
// not lift the 256 cap -- the arch/AGPR split is structural.
// Round-9: interleave BOTH sequences in every block (8 h-elems of each;
// weights 3+3 rows/wave = 192 regs/thread, unchanged). Two-phase step:
//   matvec1 -> A -> {gates1+publish1[t+1] || load h2[t]}   (h2[t] is a full
//   phase old -> first-try hit)
//   -> B -> {pre-issue h1[t+1] loads || matvec2 || verify h1[t+1] || xp stage}
//   -> C -> gates2+publish2[t+1]  (no 4th barrier; wave1 rejoins at next A)
// Each publish gets ~a full compute phase to propagate before it is read, so
// cross-XCD latency hides under the other sequence's matvec. The per-word tag
// verify doubles as the global rendezvous: publishing t+2 requires verifying
// ALL blocks' t+1, which implies their t-reads completed -> a buffer word is
// never overwritten while a reader still needs it (2-step separation).
// Retry loop reloads ONLY mismatched words (no poll storm); s_sleep backoff.
// Summation order per row identical to r7/r8 -> bit-identical output.
// ---------------------------------------------------------------------------

__global__ void init_pub_kernel(unsigned long long* __restrict__ pub) {
    // zero [2 seq][2 parity][kH] tagged words = 8192
    pub[blockIdx.x * 1024 + threadIdx.x] = 0ull;
}

// fp32 tiled GEMM: xp[t][j] = sum_k x[t][k] * Wih[j][k] + bih[j]
__global__ __launch_bounds__(256) void gemm_xp_kernel(
    const float* __restrict__ x1, const float* __restrict__ x2,
    const float* __restrict__ Wih1, const float* __restrict__ Wih2,
    const float* __restrict__ bih1, const float* __restrict__ bih2,
    float* __restrict__ xp1, float* __restrict__ xp2) {
    const float* x  = blockIdx.z ? x2   : x1;
    const float* W  = blockIdx.z ? Wih2 : Wih1;
    const float* bi = blockIdx.z ? bih2 : bih1;
    float*       xp = blockIdx.z ? xp2  : xp1;

    __shared__ float As[16][68];
    __shared__ float Bs[16][68];

    const int tid  = threadIdx.x;
    const int tx   = tid & 15, ty = tid >> 4;
    const int lrow = tid >> 2;
    const int lk   = (tid & 3) * 4;
    const int m0   = blockIdx.y * 64;
    const int n0   = blockIdx.x * 64;

    float acc[4][4] = {};

    for (int k0 = 0; k0 < kD; k0 += 16) {
        float4 av = *(const float4*)(x + (size_t)(m0 + lrow) * kD + k0 + lk);
        float4 bv = *(const float4*)(W + (size_t)(n0 + lrow) * kD + k0 + lk);
        __syncthreads();
        As[lk + 0][lrow] = av.x; As[lk + 1][lrow] = av.y;
        As[lk + 2][lrow] = av.z; As[lk + 3][lrow] = av.w;
        Bs[lk + 0][lrow] = bv.x; Bs[lk + 1][lrow] = bv.y;
        Bs[lk + 2][lrow] = bv.z; Bs[lk + 3][lrow] = bv.w;
        __syncthreads();
#pragma unroll
        for (int kk = 0; kk < 16; ++kk) {
            float4 a = *(const float4*)&As[kk][ty * 4];
            float4 b = *(const float4*)&Bs[kk][tx * 4];
            float aa[4] = {a.x, a.y, a.z, a.w};
            float bb[4] = {b.x, b.y, b.z, b.w};
#pragma unroll
            for (int i = 0; i < 4; ++i)
#pragma unroll
                for (int j = 0; j < 4; ++j)
                    acc[i][j] = fmaf(aa[i], bb[j], acc[i][j]);
        }
    }

    float4 bb4 = *(const float4*)(bi + n0 + tx * 4);
    float bArr[4] = {bb4.x, bb4.y, bb4.z, bb4.w};
#pragma unroll
    for (int i = 0; i < 4; ++i) {
        float4 o;
        o.x = acc[i][0] + bArr[0];
        o.y = acc[i][1] + bArr[1];
        o.z = acc[i][2] + bArr[2];
        o.w = acc[i][3] + bArr[3];
        *(float4*)(xp + (size_t)(m0 + ty * 4 + i) * kTH + n0 + tx * 4) = o;
    }
}

// Persistent GRU, BOTH sequences interleaved per block. 256 blocks x 512 thr.
// Block b owns h1[i0..i0+8) and h2[i0..i0+8), i0 = b*8. 8 waves x 3 rows per
// sequence per wave; lane l owns cols {e*256+4l..+4}; w[6][32] = 192 regs.
// pub layout: [seq][parity][kH] of {tag<<32 | f32 bits} (8-B relaxed atomics).
__global__ __launch_bounds__(512, 2) void gru_pair_kernel(
    const float* __restrict__ xp1, const float* __restrict__ xp2,
    const float* __restrict__ Whh1, const float* __restrict__ Whh2,
    const float* __restrict__ bhh1, const float* __restrict__ bhh2,
    unsigned long long* __restrict__ pub,   // [2][2][kH]
    float* __restrict__ hfinal) {           // [2][kH]
    const int tid  = threadIdx.x;
    const int lane = tid & 63;
    const int wv   = tid >> 6;          // 0..7
    const int b    = blockIdx.x;
    const int i0   = b * 8;

    __shared__ float h1_s[kH];
    __shared__ float h2_s[kH];
    __shared__ float hp_s[2][24];       // [seq][gate*8+elem]
    __shared__ float xp_s[2][2][24];    // [parity][seq][gate*8+elem]

    // one-time register-resident weight load: 3 rows/seq/wave
    // lr = wv*3+p in [0,24): gate g=lr>>3, elem j=lr&7, row rg=g*kH+i0+j
    float w[6][32];
    float bias[6];
#pragma unroll
    for (int p = 0; p < 3; ++p) {
        const int lr = wv * 3 + p;
        const int g  = lr >> 3, j = lr & 7;
        const int rg = g * kH + i0 + j;
        bias[p]     = bhh1[rg];
        bias[3 + p] = bhh2[rg];
        const float* w1 = Whh1 + (size_t)rg * kH;
        const float* w2 = Whh2 + (size_t)rg * kH;
#pragma unroll
        for (int e = 0; e < 8; ++e) {
            float4 v1 = *(const float4*)(w1 + e * 256 + lane * 4);
            float4 v2 = *(const float4*)(w2 + e * 256 + lane * 4);
            w[p][e * 4 + 0] = v1.x; w[p][e * 4 + 1] = v1.y;
            w[p][e * 4 + 2] = v1.z; w[p][e * 4 + 3] = v1.w;
            w[3 + p][e * 4 + 0] = v2.x; w[3 + p][e * 4 + 1] = v2.y;
            w[3 + p][e * 4 + 2] = v2.z; w[3 + p][e * 4 + 3] = v2.w;
        }
    }
    *(float4*)&h1_s[tid * 4] = make_float4(0.f, 0.f, 0.f, 0.f);
    *(float4*)&h2_s[tid * 4] = make_float4(0.f, 0.f, 0.f, 0.f);
    if (tid < 48) {                     // stage xp[0] for both sequences
        const int s_ = tid / 24, rem = tid % 24;
        const int g = rem >> 3, j = rem & 7;
        const float* xps = s_ ? xp2 : xp1;
        xp_s[0][s_][rem] = xps[(size_t)g * kH + i0 + j];
    }
    __syncthreads();

    unsigned long long* __restrict__ pub1 = pub;
    unsigned long long* __restrict__ pub2 = pub + 2 * kH;
    const int base = tid * 4;

    for (int t = 0; t < kT; ++t) {
        const int parC = t & 1;
        const int parN = parC ^ 1;
        const bool more = (t + 1 < kT);

        // ---- P1: matvec seq1 (h1_s holds h1[t]) ----
        {
            float a0 = 0.f, a1 = 0.f, a2 = 0.f;
#pragma unroll
            for (int e = 0; e < 8; ++e) {
                const float4 hv = *(const float4*)&h1_s[e * 256 + lane * 4];
                a0 = fmaf(w[0][e * 4 + 0], hv.x, a0);
                a0 = fmaf(w[0][e * 4 + 1], hv.y, a0);
                a0 = fmaf(w[0][e * 4 + 2], hv.z, a0);
                a0 = fmaf(w[0][e * 4 + 3], hv.w, a0);
                a1 = fmaf(w[1][e * 4 + 0], hv.x, a1);
                a1 = fmaf(w[1][e * 4 + 1], hv.y, a1);
                a1 = fmaf(w[1][e * 4 + 2], hv.z, a1);
                a1 = fmaf(w[1][e * 4 + 3], hv.w, a1);
                a2 = fmaf(w[2][e * 4 + 0], hv.x, a2);
                a2 = fmaf(w[2][e * 4 + 1], hv.y, a2);
                a2 = fmaf(w[2][e * 4 + 2], hv.z, a2);
                a2 = fmaf(w[2][e * 4 + 3], hv.w, a2);
            }
            float acc3[3] = {a0, a1, a2};
#pragma unroll
            for (int p = 0; p < 3; ++p) {
                float a = acc3[p];
#pragma unroll
                for (int off = 32; off; off >>= 1) a += __shfl_down(a, off, 64);
                if (lane == 0) hp_s[0][wv * 3 + p] = a + bias[p];
            }
        }
        __syncthreads();   // (A) hp1 ready; h1_s/h2_s reads of prev step done

        if (wv == 0 && lane < 8) {      // gates1 + fire-and-forget publish
            const int i = i0 + lane;
            const float xr = xp_s[parC][0][lane];
            const float xz = xp_s[parC][0][8 + lane];
            const float xn = xp_s[parC][0][16 + lane];
            const float r = 1.f / (1.f + expf(-(xr + hp_s[0][lane])));
            const float z = 1.f / (1.f + expf(-(xz + hp_s[0][8 + lane])));
            const float n = tanhf(xn + r * hp_s[0][16 + lane]);
            const float hn = (1.f - z) * n + z * h1_s[i];
            if (t == kT - 1) {
                hfinal[i] = hn;
            } else {
                const unsigned long long pk =
                    ((unsigned long long)(unsigned)(t + 1) << 32) |
                    (unsigned long long)__float_as_uint(hn);
                __hip_atomic_store(&pub1[(size_t)parN * kH + i], pk,
                                   __ATOMIC_RELAXED, __HIP_MEMORY_SCOPE_AGENT);
            }
        }
        // load h2[t] -> h2_s (published one full phase ago: first try hits)
        {
            const unsigned long long* src = pub2 + (size_t)parC * kH;
            const unsigned tgt = (unsigned)t;
            unsigned long long v0, v1, v2, v3;
            v0 = __hip_atomic_load(&src[base + 0], __ATOMIC_RELAXED,
                                   __HIP_MEMORY_SCOPE_AGENT);
            v1 = __hip_atomic_load(&src[base + 1], __ATOMIC_RELAXED,
                                   __HIP_MEMORY_SCOPE_AGENT);
            v2 = __hip_atomic_load(&src[base + 2], __ATOMIC_RELAXED,
                                   __HIP_MEMORY_SCOPE_AGENT);
            v3 = __hip_atomic_load(&src[base + 3], __ATOMIC_RELAXED,
                                   __HIP_MEMORY_SCOPE_AGENT);
            bool d0 = (unsigned)(v0 >> 32) == tgt;
            bool d1 = (unsigned)(v1 >> 32) == tgt;
            bool d2 = (unsigned)(v2 >> 32) == tgt;
            bool d3 = (unsigned)(v3 >> 32) == tgt;
            while (!(d0 & d1 & d2 & d3)) {   // rare: reload ONLY missing words
                __builtin_amdgcn_s_sleep(1);
                if (!d0) { v0 = __hip_atomic_load(&src[base + 0], __ATOMIC_RELAXED, __HIP_MEMORY_SCOPE_AGENT); d0 = (unsigned)(v0 >> 32) == tgt; }
                if (!d1) { v1 = __hip_atomic_load(&src[base + 1], __ATOMIC_RELAXED, __HIP_MEMORY_SCOPE_AGENT); d1 = (unsigned)(v1 >> 32) == tgt; }
                if (!d2) { v2 = __hip_atomic_load(&src[base + 2], __ATOMIC_RELAXED, __HIP_MEMORY_SCOPE_AGENT); d2 = (unsigned)(v2 >> 32) == tgt; }
                if (!d3) { v3 = __hip_atomic_load(&src[base + 3], __ATOMIC_RELAXED, __HIP_MEMORY_SCOPE_AGENT); d3 = (unsigned)(v3 >> 32) == tgt; }
            }
            float4 hv;
            hv.x = __uint_as_float((unsigned)v0);
            hv.y = __uint_as_float((unsigned)v1);
            hv.z = __uint_as_float((unsigned)v2);
            hv.w = __uint_as_float((unsigned)v3);
            *(float4*)&h2_s[base] = hv;
        }
        __syncthreads();   // (B) h2_s ready; gates1 consumed h1_s

        // pre-issue h1[t+1] loads: latency hides under matvec2
        unsigned long long q0 = 0, q1 = 0, q2 = 0, q3 = 0;
        const unsigned long long* src1 = pub1 + (size_t)parN * kH;
        if (more) {
            q0 = __hip_atomic_load(&src1[base + 0], __ATOMIC_RELAXED, __HIP_MEMORY_SCOPE_AGENT);
            q1 = __hip_atomic_load(&src1[base + 1], __ATOMIC_RELAXED, __HIP_MEMORY_SCOPE_AGENT);
            q2 = __hip_atomic_load(&src1[base + 2], __ATOMIC_RELAXED, __HIP_MEMORY_SCOPE_AGENT);
            q3 = __hip_atomic_load(&src1[base + 3], __ATOMIC_RELAXED, __HIP_MEMORY_SCOPE_AGENT);
        }
        // wave2: issue xp[t+1] reads early (LDS write deferred past matvec2)
        float xpv = 0.f;
        int xs_ = 0, xrem = 0;
        if (more && wv == 2 && lane < 48) {
            xs_ = lane / 24; xrem = lane % 24;
            const int g = xrem >> 3, j = xrem & 7;
            const float* xps = xs_ ? xp2 : xp1;
            xpv = xps[(size_t)(t + 1) * kTH + (size_t)g * kH + i0 + j];
        }

        // ---- P2: matvec seq2 (h2_s holds h2[t]) ----
        {
            float a0 = 0.f, a1 = 0.f, a2 = 0.f;
#pragma unroll
            for (int e = 0; e < 8; ++e) {
                const float4 hv = *(const float4*)&h2_s[e * 256 + lane * 4];
                a0 = fmaf(w[3][e * 4 + 0], hv.x, a0);
                a0 = fmaf(w[3][e * 4 + 1], hv.y, a0);
                a0 = fmaf(w[3][e * 4 + 2], hv.z, a0);
                a0 = fmaf(w[3][e * 4 + 3], hv.w, a0);
                a1 = fmaf(w[4][e * 4 + 0], hv.x, a1);
                a1 = fmaf(w[4][e * 4 + 1], hv.y, a1);
                a1 = fmaf(w[4][e * 4 + 2], hv.z, a1);
                a1 = fmaf(w[4][e * 4 + 3], hv.w, a1);
                a2 = fmaf(w[5][e * 4 + 0], hv.x, a2);
                a2 = fmaf(w[5][e * 4 + 1], hv.y, a2);
                a2 = fmaf(w[5][e * 4 + 2], hv.z, a2);
                a2 = fmaf(w[5][e * 4 + 3], hv.w, a2);
            }
            float acc3[3] = {a0, a1, a2};
#pragma unroll
            for (int p = 0; p < 3; ++p) {
                float a = acc3[p];
#pragma unroll
                for (int off = 32; off; off >>= 1) a += __shfl_down(a, off, 64);
                if (lane == 0) hp_s[1][wv * 3 + p] = a + bias[3 + p];
            }
        }
        // verify h1[t+1] (published ~a phase ago by every block's wave0)
        if (more) {
            const unsigned tgt = (unsigned)(t + 1);
            bool d0 = (unsigned)(q0 >> 32) == tgt;
            bool d1 = (unsigned)(q1 >> 32) == tgt;
            bool d2 = (unsigned)(q2 >> 32) == tgt;
            bool d3 = (unsigned)(q3 >> 32) == tgt;
            while (!(d0 & d1 & d2 & d3)) {
                __builtin_amdgcn_s_sleep(1);
                if (!d0) { q0 = __hip_atomic_load(&src1[base + 0], __ATOMIC_RELAXED, __HIP_MEMORY_SCOPE_AGENT); d0 = (unsigned)(q0 >> 32) == tgt; }
                if (!d1) { q1 = __hip_atomic_load(&src1[base + 1], __ATOMIC_RELAXED, __HIP_MEMORY_SCOPE_AGENT); d1 = (unsigned)(q1 >> 32) == tgt; }
                if (!d2) { q2 = __hip_atomic_load(&src1[base + 2], __ATOMIC_RELAXED, __HIP_MEMORY_SCOPE_AGENT); d2 = (unsigned)(q2 >> 32) == tgt; }
                if (!d3) { q3 = __hip_atomic_load(&src1[base + 3], __ATOMIC_RELAXED, __HIP_MEMORY_SCOPE_AGENT); d3 = (unsigned)(q3 >> 32) == tgt; }
            }
            float4 hv;
            hv.x = __uint_as_float((unsigned)q0);
            hv.y = __uint_as_float((unsigned)q1);
            hv.z = __uint_as_float((unsigned)q2);
            hv.w = __uint_as_float((unsigned)q3);
            *(float4*)&h1_s[base] = hv;
        }
        if (more && wv == 2 && lane < 48) xp_s[parN][xs_][xrem] = xpv;
        __syncthreads();   // (C) hp2, h1_s, xp[t+1] ready

        if (wv == 1 && lane < 8) {      // gates2; others roll into next P1
            const int i = i0 + lane;
            const float xr = xp_s[parC][1][lane];
            const float xz = xp_s[parC][1][8 + lane];
            const float xn = xp_s[parC][1][16 + lane];
            const float r = 1.f / (1.f + expf(-(xr + hp_s[1][lane])));
            const float z = 1.f / (1.f + expf(-(xz + hp_s[1][8 + lane])));
            const float n = tanhf(xn + r * hp_s[1][16 + lane]);
            const float hn = (1.f - z) * n + z * h2_s[i];
            if (t == kT - 1) {
                hfinal[kH + i] = hn;
            } else {
                const unsigned long long pk =
                    ((unsigned long long)(unsigned)(t + 1) << 32) |
                    (unsigned long long)__float_as_uint(hn);
                __hip_atomic_store(&pub2[(size_t)parN * kH + i], pk,
                                   __ATOMIC_RELAXED, __HIP_MEMORY_SCOPE_AGENT);
            }
        }
        // no 4th barrier: wave1's h2_s/hp_s/xp_s reads are protected because
        // next-step writers pass barrier (A)/(B) only after wave1 arrives.
    }
}

// fc1(relu) -> fc2 -> log_softmax, single block of 256 threads
__global__ __launch_bounds__(256) void head_kernel(
    const float* __restrict__ h1, const float* __restrict__ h2,
    const float* __restrict__ fc1w, const float* __restrict__ fc1b,
    const float* __restrict__ fc2w, const float* __restrict__ fc2b,
    float* __restrict__ out) {
    __shared__ float cat[2 * kH];
    __shared__ float o1[256];
    __shared__ float logits[3];
    const int tid  = threadIdx.x;
    const int lane = tid & 63;
    const int wave = tid >> 6;

    for (int k = tid; k < kH; k += 256) {
        cat[k]      = h1[k];
        cat[kH + k] = h2[k];
    }
    __syncthreads();

    for (int r = wave; r < 256; r += 4) {
        const float* wr = fc1w + (size_t)r * (2 * kH);
        float acc = 0.f;
        for (int j = lane; j < 2 * kH; j += 64) acc = fmaf(wr[j], cat[j], acc);
#pragma unroll
        for (int off = 32; off; off >>= 1) acc += __shfl_down(acc, off, 64);
        if (lane == 0) o1[r] = fmaxf(acc + fc1b[r], 0.f);
    }
    __syncthreads();

    if (tid < 3) {
        float acc = fc2b[tid];
        const float* wr = fc2w + tid * 256;
        for (int j = 0; j < 256; ++j) acc = fmaf(wr[j], o1[j], acc);
        logits[tid] = acc;
    }
    __syncthreads();

    if (tid == 0) {
        float m = fmaxf(logits[0], fmaxf(logits[1], logits[2]));
        float s = expf(logits[0] - m) + expf(logits[1] - m) + expf(logits[2] - m);
        float ls = logf(s);
        out[0] = logits[0] - m - ls;
        out[1] = logits[1] - m - ls;
        out[2] = logits[2] - m - ls;
    }
}

extern "C" void kernel_launch(void* const* d_in, const int* in_sizes, int n_in,
                              void* d_out, int out_size, void* d_ws,
                              size_t ws_size, hipStream_t stream) {
    const float* x1   = (const float*)d_in[0];
    const float* x2   = (const float*)d_in[1];
    const float* Wih1 = (const float*)d_in[2];
    const float* Whh1 = (const float*)d_in[3];
    const float* bih1 = (const float*)d_in[4];
    const float* bhh1 = (const float*)d_in[5];
    const float* Wih2 = (const float*)d_in[6];
    const float* Whh2 = (const float*)d_in[7];
    const float* bih2 = (const float*)d_in[8];
    const float* bhh2 = (const float*)d_in[9];
    const float* fc1w = (const float*)d_in[10];
    const float* fc1b = (const float*)d_in[11];
    const float* fc2w = (const float*)d_in[12];
    const float* fc2b = (const float*)d_in[13];
    float* out = (float*)d_out;

    char* ws = (char*)d_ws;
    float* xp1 = (float*)ws;
    float* xp2 = xp1 + (size_t)kT * kTH;
    unsigned long long* pub = (unsigned long long*)(xp2 + (size_t)kT * kTH);
    float* hfinal = (float*)(pub + 4 * kH);   // [2][kH]

    init_pub_kernel<<<8, 1024, 0, stream>>>(pub);

    gemm_xp_kernel<<<dim3(kTH / 64, kT / 64, 2), 256, 0, stream>>>(
        x1, x2, Wih1, Wih2, bih1, bih2, xp1, xp2);

    gru_pair_kernel<<<dim3(kNB), dim3(512), 0, stream>>>(
        xp1, xp2, Whh1, Whh2, bhh1, bhh2, pub, hfinal);

    head_kernel<<<1, 256, 0, stream>>>(hfinal, hfinal + kH, fc1w, fc1b, fc2w,
                                       fc2b, out);
}